// Round 1
// baseline (2149.290 us; speedup 1.0000x reference)
//
#include <hip/hip_runtime.h>
#include <stdint.h>

// HeteroscedasticSoftmax: out = mean_{s<100} softmax(logits + eps_s * exp(log_std), axis=C)
// eps reproduces jax.random.normal under the partitionable threefry scheme (verified R0/R1):
//   key_s  = threefry2x32((0,1), (0, s))
//   bits_j = w0 ^ w1 of threefry2x32(key_s, (0, j)), j = flat element index
//   u = bitcast((bits>>9)|0x3F800000) scaled; eps = sqrt2*erfinv(u) (coeff-folded)
//
// R3: occupancy attack, take 2. R2's LDS staging (39936 B/block) capped occupancy at
// 4 blocks/CU = 4 waves/SIMD; real VALU busy ~55% (VALUBusy=110 is the gfx94x SIMD-16
// formula, x2 off on gfx950's SIMD-32). Fix:
//  - split the 19 channels across the 4 lanes of a quad (5/5/5/4 + 1 dead padded slot)
//  - softmax max/sum reduced across the quad with DPP quad_perm swaps (no LDS, no lgkm)
//  - all per-thread state (lgE/sdE/acc/z = 20 floats) lives in registers: ~40 VGPR
//  - __launch_bounds__(256,8) -> <=64 VGPR -> 8 waves/SIMD; LDS = 800 B (key table only)

#define NCH    19
#define HW     65536
#define NSAMP  100

__device__ __forceinline__ uint32_t rotl(uint32_t x, uint32_t r) {
  return __builtin_amdgcn_alignbit(x, x, 32u - r);
}

__device__ __forceinline__ void tf2x32_full(uint32_t k0, uint32_t k1,
                                            uint32_t x0, uint32_t x1,
                                            uint32_t& o0, uint32_t& o1) {
  const uint32_t k2 = k0 ^ k1 ^ 0x1BD11BDAu;
#define TFR(r) { x0 += x1; x1 = rotl(x1, r) ^ x0; }
  x0 += k0; x1 += k1;
  TFR(13u) TFR(15u) TFR(26u) TFR(6u)
  x0 += k1; x1 += k2 + 1u;
  TFR(17u) TFR(29u) TFR(16u) TFR(24u)
  x0 += k2; x1 += k0 + 2u;
  TFR(13u) TFR(15u) TFR(26u) TFR(6u)
  x0 += k0; x1 += k1 + 3u;
  TFR(17u) TFR(29u) TFR(16u) TFR(24u)
  x0 += k1; x1 += k2 + 4u;
  TFR(13u) TFR(15u) TFR(26u) TFR(6u)
  x0 += k2; x1 += k0 + 5u;
#undef TFR
  o0 = x0; o1 = x1;
}

// Hot-path threefry, x0_in = 0, returns o0^o1. Keys wave-uniform (SGPR).
__device__ __forceinline__ uint32_t tf_fold(uint32_t k0, uint32_t k1, uint32_t k2,
                                            uint32_t x1in) {
  uint32_t x0, x1;
  x1 = x1in + k1;
  x0 = k0 + x1;
  x1 = rotl(x1, 13u) ^ x0;
  x0 += x1; x1 = rotl(x1, 15u) ^ x0;
  x0 += x1; x1 = rotl(x1, 26u) ^ x0;
  x0 += x1; x1 = rotl(x1,  6u) ^ x0;
  x1 += k2 + 1u;
  x0 = x0 + k1 + x1; x1 = rotl(x1, 17u) ^ x0;
  x0 += x1; x1 = rotl(x1, 29u) ^ x0;
  x0 += x1; x1 = rotl(x1, 16u) ^ x0;
  x0 += x1; x1 = rotl(x1, 24u) ^ x0;
  x1 += k0 + 2u;
  x0 = x0 + k2 + x1; x1 = rotl(x1, 13u) ^ x0;
  x0 += x1; x1 = rotl(x1, 15u) ^ x0;
  x0 += x1; x1 = rotl(x1, 26u) ^ x0;
  x0 += x1; x1 = rotl(x1,  6u) ^ x0;
  x1 += k1 + 3u;
  x0 = x0 + k0 + x1; x1 = rotl(x1, 17u) ^ x0;
  x0 += x1; x1 = rotl(x1, 29u) ^ x0;
  x0 += x1; x1 = rotl(x1, 16u) ^ x0;
  x0 += x1; x1 = rotl(x1, 24u) ^ x0;
  x1 += k2 + 4u;
  x0 = x0 + k1 + x1; x1 = rotl(x1, 13u) ^ x0;
  x0 += x1; x1 = rotl(x1, 15u) ^ x0;
  x0 += x1; x1 = rotl(x1, 26u) ^ x0;
  x0 += x1; x1 = rotl(x1,  6u) ^ x0;
  return (x0 + k2) ^ (x1 + k0 + 5u);
}

// sqrt(2)*erfinv(u); central poly evaluated directly in t = log2(1-u^2)
// (alpha = -ln2 folded into coefficients; center beta = 2.5/alpha).
__device__ __forceinline__ float bits_to_eps(uint32_t bits) {
  const float lo = -0.99999994f;  // nextafter(-1, 0)
  // x = bitcast((bits>>9)|0x3F800000) in [1,2); u = 2x - 2 + lo
  float x = __uint_as_float((bits >> 9) | 0x3F800000u);
  float u = fmaf(x, 2.0f, -2.99999994f);
  u = fmaxf(u, lo);
  float t = __builtin_amdgcn_logf(fmaf(-u, u, 1.0f));  // log2(1-u^2), <= 0
  float p;
  if (t > -7.2135401f) {          // w = -ln2*t < 5  (central branch)
    float tw = t + 3.6067376f;    // t - beta
    p = 2.1176667e-09f;
    p = fmaf(p, tw, -3.7319753e-08f);
    p = fmaf(p, tw, -5.5262077e-07f);
    p = fmaf(p, tw, 9.9370361e-07f);
    p = fmaf(p, tw, 7.1355918e-05f);
    p = fmaf(p, tw, 5.9046852e-04f);
    p = fmaf(p, tw, -2.8386612e-03f);
    p = fmaf(p, tw, -2.4177230e-01f);
    p = fmaf(p, tw, 2.1233141e+00f);
  } else {                        // tail (rare): reconstruct w
    float w = -0.69314718f * t;
    w = __fsqrt_rn(w) - 3.0f;
    p = -2.8314594e-04f;
    p = fmaf(p, w, 1.4276565e-04f);
    p = fmaf(p, w, 1.9082604e-03f);
    p = fmaf(p, w, -5.1950124e-03f);
    p = fmaf(p, w, 8.1168916e-03f);
    p = fmaf(p, w, -1.0779791e-02f);
    p = fmaf(p, w, 1.3348577e-02f);
    p = fmaf(p, w, 1.4165810e+00f);
    p = fmaf(p, w, 4.0064324e+00f);
  }
  return p * u;
}

// DPP quad swaps: lane ^ 1 and lane ^ 2 within each quad. 1 VALU op each, no LDS.
__device__ __forceinline__ float dpp_swap1(float v) {
  return __int_as_float(
      __builtin_amdgcn_mov_dpp(__float_as_int(v), 0xB1, 0xF, 0xF, true));
}
__device__ __forceinline__ float dpp_swap2(float v) {
  return __int_as_float(
      __builtin_amdgcn_mov_dpp(__float_as_int(v), 0x4E, 0xF, 0xF, true));
}

__global__ __launch_bounds__(256, 8)
void HeteroscedasticSoftmax_kernel(const float* __restrict__ in,
                                   float* __restrict__ out) {
  __shared__ uint2 skey[NSAMP];

  const int t = threadIdx.x;
  if (t < NSAMP) {
    uint32_t a, b;
    tf2x32_full(0u, 1u, 0u, (uint32_t)t, a, b);
    skey[t] = make_uint2(a, b);
  }

  // 4 lanes (a quad) share one pixel; lane `par` owns channels c = 4i+par.
  const int gid = blockIdx.x * 64 + (t >> 2);   // pixel id
  const int par = t & 3;
  const int b_  = gid >> 16;
  const int hw  = gid & 65535;

  const float L2E = 1.4426950408889634f;
  const float* pin = in + (size_t)b_ * (2 * NCH * HW) + hw;
  float lgE[5], sdE[5], acc[5];
#pragma unroll
  for (int i = 0; i < 5; ++i) {
    const int c  = 4 * i + par;
    const int cc = (c < NCH) ? c : 0;          // clamp load (c=19 pad slot)
    const float lg = pin[cc * HW];
    const float ls = pin[(NCH + cc) * HW];
    lgE[i] = (c < NCH) ? lg * L2E : -1.0e30f;  // dead slot: z=-1e30 -> exp2 -> 0
    sdE[i] = (c < NCH) ? __expf(ls) * L2E : 0.0f;
    acc[i] = 0.0f;
  }
  __syncthreads();

  const uint32_t jb = (uint32_t)(b_ * NCH) * (uint32_t)HW
                    + (uint32_t)hw + (uint32_t)(par * HW);

#pragma unroll 1
  for (int s = 0; s < NSAMP; ++s) {
    const uint2 kk = skey[s];
    const uint32_t k0 = __builtin_amdgcn_readfirstlane(kk.x);
    const uint32_t k1 = __builtin_amdgcn_readfirstlane(kk.y);
    const uint32_t k2 = k0 ^ k1 ^ 0x1BD11BDAu;

    float z[5];
#pragma unroll
    for (int i = 0; i < 5; ++i) {
      const uint32_t bits = tf_fold(k0, k1, k2, jb + (uint32_t)(i * 4 * HW));
      const float eps = bits_to_eps(bits);
      z[i] = fmaf(eps, sdE[i], lgE[i]);   // (lg + eps*sd) * log2(e)
    }

    // max over 19 channels: local 5, then quad reduce (2 DPP + 2 max)
    float m = fmaxf(fmaxf(fmaxf(z[0], z[1]), fmaxf(z[2], z[3])), z[4]);
    m = fmaxf(m, dpp_swap1(m));
    m = fmaxf(m, dpp_swap2(m));

#pragma unroll
    for (int i = 0; i < 5; ++i) z[i] = __builtin_amdgcn_exp2f(z[i] - m);

    float ss = (z[0] + z[1]) + (z[2] + z[3]) + z[4];
    ss += dpp_swap1(ss);
    ss += dpp_swap2(ss);
    const float r = __builtin_amdgcn_rcpf(ss);

#pragma unroll
    for (int i = 0; i < 5; ++i) acc[i] = fmaf(z[i], r, acc[i]);
  }

  float* pout = out + (size_t)b_ * (NCH * HW) + hw;
#pragma unroll
  for (int i = 0; i < 5; ++i) {
    const int c = 4 * i + par;
    if (c < NCH) pout[c * HW] = acc[i] * 0.01f;
  }
}

extern "C" void kernel_launch(void* const* d_in, const int* in_sizes, int n_in,
                              void* d_out, int out_size, void* d_ws, size_t ws_size,
                              hipStream_t stream) {
  const float* in = (const float*)d_in[0];
  float* out = (float*)d_out;
  // 8*65536 pixels / 64 pixels-per-block = 8192 blocks
  HeteroscedasticSoftmax_kernel<<<8192, 256, 0, stream>>>(in, out);
}

// Round 3
// 2110.859 us; speedup vs baseline: 1.0182x; 1.0182x over previous
//
#include <hip/hip_runtime.h>
#include <stdint.h>

// HeteroscedasticSoftmax: out = mean_{s<100} softmax(logits + eps_s * exp(log_std), axis=C)
// eps reproduces jax.random.normal under the partitionable threefry scheme (verified R0/R1):
//   key_s  = threefry2x32((0,1), (0, s))
//   bits_j = w0 ^ w1 of threefry2x32(key_s, (0, j)), j = flat element index
//   u from top 23 bits; eps = sqrt2*erfinv(u) (coeff-folded, log2-domain central poly)
//
// R5 = R4 with the u=-1 guard restored. R4 NaN'd: -2.99999994f rounds to -3.0f
// (float spacing 2^-22 near 3), so u = 2x-3.0 exactly, and bits>>9==0 gives u=-1.0
// -> log2(0) -> inf -> NaN. fmaxf(u, -0.99999994f) (representable) is mandatory;
// no constant in (2.99999976, 3.0) exists and y-C is Sterbenz-exact, so the clamp
// cannot be folded away. Numerics now bit-identical to verified R2.
// Kept R4 cuts (vs R2):
//  - 19 channels/thread, lg/sd/acc in registers (no LDS staging: removes 19
//    ds_read_b64 issue slots + lgkm waits per sample)
//  - k1 + c*HW folded to SALU (wave-uniform): 1 VALU add per tf_fold entry, not 2
//  - (bits>>9)|exp via one v_alignbit: (0x80:bits)>>9 = 0x40000000|(bits>>9), y in [2,4)
//    = 2x, so u = y - 3.0f is a single VOP2 add (exact, == R2's fmaf)
//  - 19-way max restructured in triples to coax v_max3_f32 (9 ops vs 18)
//  - tail branch predicated on omu2 (resolves before the v_log result lands)

#define NCH    19
#define HW     65536
#define NSAMP  100

__device__ __forceinline__ uint32_t rotl(uint32_t x, uint32_t r) {
  return __builtin_amdgcn_alignbit(x, x, 32u - r);
}

__device__ __forceinline__ void tf2x32_full(uint32_t k0, uint32_t k1,
                                            uint32_t x0, uint32_t x1,
                                            uint32_t& o0, uint32_t& o1) {
  const uint32_t k2 = k0 ^ k1 ^ 0x1BD11BDAu;
#define TFR(r) { x0 += x1; x1 = rotl(x1, r) ^ x0; }
  x0 += k0; x1 += k1;
  TFR(13u) TFR(15u) TFR(26u) TFR(6u)
  x0 += k1; x1 += k2 + 1u;
  TFR(17u) TFR(29u) TFR(16u) TFR(24u)
  x0 += k2; x1 += k0 + 2u;
  TFR(13u) TFR(15u) TFR(26u) TFR(6u)
  x0 += k0; x1 += k1 + 3u;
  TFR(17u) TFR(29u) TFR(16u) TFR(24u)
  x0 += k1; x1 += k2 + 4u;
  TFR(13u) TFR(15u) TFR(26u) TFR(6u)
  x0 += k2; x1 += k0 + 5u;
#undef TFR
  o0 = x0; o1 = x1;
}

// Hot-path threefry. x1pre = counter + k1 (k1-part folded on SALU by caller).
// Keys wave-uniform (SGPR). Returns o0 ^ o1.
__device__ __forceinline__ uint32_t tf_fold(uint32_t k0, uint32_t k1, uint32_t k2,
                                            uint32_t x1pre) {
  uint32_t x0, x1;
  x1 = x1pre;
  x0 = k0 + x1;
  x1 = rotl(x1, 13u) ^ x0;
  x0 += x1; x1 = rotl(x1, 15u) ^ x0;
  x0 += x1; x1 = rotl(x1, 26u) ^ x0;
  x0 += x1; x1 = rotl(x1,  6u) ^ x0;
  x1 += k2 + 1u;
  x0 = x0 + k1 + x1; x1 = rotl(x1, 17u) ^ x0;
  x0 += x1; x1 = rotl(x1, 29u) ^ x0;
  x0 += x1; x1 = rotl(x1, 16u) ^ x0;
  x0 += x1; x1 = rotl(x1, 24u) ^ x0;
  x1 += k0 + 2u;
  x0 = x0 + k2 + x1; x1 = rotl(x1, 13u) ^ x0;
  x0 += x1; x1 = rotl(x1, 15u) ^ x0;
  x0 += x1; x1 = rotl(x1, 26u) ^ x0;
  x0 += x1; x1 = rotl(x1,  6u) ^ x0;
  x1 += k1 + 3u;
  x0 = x0 + k0 + x1; x1 = rotl(x1, 17u) ^ x0;
  x0 += x1; x1 = rotl(x1, 29u) ^ x0;
  x0 += x1; x1 = rotl(x1, 16u) ^ x0;
  x0 += x1; x1 = rotl(x1, 24u) ^ x0;
  x1 += k2 + 4u;
  x0 = x0 + k1 + x1; x1 = rotl(x1, 13u) ^ x0;
  x0 += x1; x1 = rotl(x1, 15u) ^ x0;
  x0 += x1; x1 = rotl(x1, 26u) ^ x0;
  x0 += x1; x1 = rotl(x1,  6u) ^ x0;
  return (x0 + k2) ^ (x1 + k0 + 5u);
}

// sqrt(2)*erfinv(u); central poly evaluated directly in t = log2(1-u^2)
// (alpha = -ln2 folded into coefficients; center beta = 2.5/alpha).
__device__ __forceinline__ float bits_to_eps(uint32_t bits) {
  // y = bitcast(0x40000000 | (bits>>9)) in [2,4) == 2x; one alignbit, no shift+or.
  float y = __uint_as_float(__builtin_amdgcn_alignbit(0x80u, bits, 9u));
  float u = y - 3.0f;                  // exact (Sterbenz); in [-1.0, 0.99999976]
  u = fmaxf(u, -0.99999994f);          // REQUIRED: u=-1.0 at bits>>9==0 -> log2(0) -> NaN
  float omu2 = fmaf(-u, u, 1.0f);      // 1 - u^2 >= ~1.19e-7 > 0
  float t = __builtin_amdgcn_logf(omu2);   // log2(1-u^2), <= 0
  float p;
  if (omu2 > 0.0067379470f) {   // == t > -7.2135401 (central, w = -ln2*t < 5)
    float tw = t + 3.6067376f;  // t - beta
    p = 2.1176667e-09f;
    p = fmaf(p, tw, -3.7319753e-08f);
    p = fmaf(p, tw, -5.5262077e-07f);
    p = fmaf(p, tw, 9.9370361e-07f);
    p = fmaf(p, tw, 7.1355918e-05f);
    p = fmaf(p, tw, 5.9046852e-04f);
    p = fmaf(p, tw, -2.8386612e-03f);
    p = fmaf(p, tw, -2.4177230e-01f);
    p = fmaf(p, tw, 2.1233141e+00f);
  } else {                      // tail (rare, ~0.34% of lanes): reconstruct w
    float w = -0.69314718f * t;
    w = __fsqrt_rn(w) - 3.0f;
    p = -2.8314594e-04f;
    p = fmaf(p, w, 1.4276565e-04f);
    p = fmaf(p, w, 1.9082604e-03f);
    p = fmaf(p, w, -5.1950124e-03f);
    p = fmaf(p, w, 8.1168916e-03f);
    p = fmaf(p, w, -1.0779791e-02f);
    p = fmaf(p, w, 1.3348577e-02f);
    p = fmaf(p, w, 1.4165810e+00f);
    p = fmaf(p, w, 4.0064324e+00f);
  }
  return p * u;
}

__device__ __forceinline__ float max3(float a, float b, float c) {
  return fmaxf(fmaxf(a, b), c);   // clang fuses to v_max3_f32
}

__global__ __launch_bounds__(256, 4)
void HeteroscedasticSoftmax_kernel(const float* __restrict__ in,
                                   float* __restrict__ out) {
  __shared__ uint2 skey[NSAMP];

  const int t = threadIdx.x;
  if (t < NSAMP) {
    uint32_t a, b;
    tf2x32_full(0u, 1u, 0u, (uint32_t)t, a, b);
    skey[t] = make_uint2(a, b);
  }

  const int gid = blockIdx.x * 256 + t;    // one pixel per thread
  const int b_  = gid >> 16;
  const int hw  = gid & 65535;

  const float L2E = 1.4426950408889634f;
  const float* pin = in + (size_t)b_ * (2 * NCH * HW) + hw;
  float lgE[NCH], sdE[NCH], acc[NCH];
#pragma unroll
  for (int c = 0; c < NCH; ++c) {
    const float lg = pin[c * HW];
    const float ls = pin[(NCH + c) * HW];
    lgE[c] = lg * L2E;
    sdE[c] = __expf(ls) * L2E;
    acc[c] = 0.0f;
  }
  __syncthreads();

  const uint32_t jbase = (uint32_t)(b_ * NCH) * (uint32_t)HW + (uint32_t)hw;

#pragma unroll 1
  for (int s = 0; s < NSAMP; ++s) {
    const uint2 kk = skey[s];
    const uint32_t k0 = __builtin_amdgcn_readfirstlane(kk.x);
    const uint32_t k1 = __builtin_amdgcn_readfirstlane(kk.y);
    const uint32_t k2 = k0 ^ k1 ^ 0x1BD11BDAu;

    float z[NCH];
#pragma unroll
    for (int c = 0; c < NCH; ++c) {
      // k1 + c*HW is wave-uniform -> SALU; only one VALU add feeds tf_fold.
      const uint32_t k1c = k1 + (uint32_t)(c * HW);
      const uint32_t bits = tf_fold(k0, k1, k2, jbase + k1c);
      const float eps = bits_to_eps(bits);
      z[c] = fmaf(eps, sdE[c], lgE[c]);   // (lg + eps*sd) * log2(e)
    }

    // 19-way max in triples: 9 v_max3_f32
    float a0 = max3(z[0],  z[1],  z[2]);
    float a1 = max3(z[3],  z[4],  z[5]);
    float a2 = max3(z[6],  z[7],  z[8]);
    float a3 = max3(z[9],  z[10], z[11]);
    float a4 = max3(z[12], z[13], z[14]);
    float a5 = max3(z[15], z[16], z[17]);
    float b0 = max3(a0, a1, a2);
    float b1 = max3(a3, a4, a5);
    const float m = max3(b0, b1, z[18]);

#pragma unroll
    for (int c = 0; c < NCH; ++c) z[c] = __builtin_amdgcn_exp2f(z[c] - m);

    float s0 = z[0] + z[1],  s1 = z[2] + z[3];
    float s2 = z[4] + z[5],  s3 = z[6] + z[7];
    float s4 = z[8] + z[9],  s5 = z[10] + z[11];
    float s6 = z[12] + z[13], s7 = z[14] + z[15];
    float s8 = z[16] + z[17];
    s0 += s1; s2 += s3; s4 += s5; s6 += s7; s8 += z[18];
    s0 += s2; s4 += s6;
    s0 += s4;
    const float r = __builtin_amdgcn_rcpf(s0 + s8);

#pragma unroll
    for (int c = 0; c < NCH; ++c) acc[c] = fmaf(z[c], r, acc[c]);
  }

  float* pout = out + (size_t)b_ * (NCH * HW) + hw;
#pragma unroll
  for (int c = 0; c < NCH; ++c) pout[c * HW] = acc[c] * 0.01f;
}

extern "C" void kernel_launch(void* const* d_in, const int* in_sizes, int n_in,
                              void* d_out, int out_size, void* d_ws, size_t ws_size,
                              hipStream_t stream) {
  const float* in = (const float*)d_in[0];
  float* out = (float*)d_out;
  HeteroscedasticSoftmax_kernel<<<2048, 256, 0, stream>>>(in, out);
}